// Round 2
// baseline (181.974 us; speedup 1.0000x reference)
//
#include <hip/hip_runtime.h>

// Problem constants (from reference setup_inputs).
constexpr int B = 8;
constexpr int N = 16384;
constexpr int M = 1024;
constexpr int C = 256;

// One block = 256 query points (phase 1: 1 thread/point) and then
// 256 channels (phase 2: 1 thread/channel, looping over the block's points).
__global__ __launch_bounds__(256) void upsample_idw_kernel(
    const float* __restrict__ xyz,          // [B,N,3]
    const float* __restrict__ sxyz,         // [B,M,3]
    const float* __restrict__ feats,        // [B,M,C]
    const int*   __restrict__ masks,        // [B,N]
    float*       __restrict__ out)          // [B,N,C]
{
    const int tid   = threadIdx.x;
    const int blk   = blockIdx.x;
    const int b     = blk >> 6;             // 16384/256 = 64 blocks per batch
    const int nbase = (blk & 63) << 8;      // first point of this block (within batch)
    const int n     = nbase + tid;

    // ---- Phase 1: per-point top-3 nearest of M candidates ----
    const float* xp = xyz + ((size_t)b * N + n) * 3;
    const float x = xp[0], y = xp[1], z = xp[2];
    const int valid = masks[(size_t)b * N + n];

    const float* sp = sxyz + (size_t)b * (M * 3);   // wave-uniform reads below

    // Top-3 smallest distances, tracked exactly (no key packing).
    // Distance arithmetic must BIT-MATCH the reference:
    //   d = (dx*dx + dy*dy) + dz*dz, separately-rounded f32 ops (no fma).
    float d0 = __builtin_inff(), d1 = __builtin_inff(), d2 = __builtin_inff();
    int   i0 = 0, i1 = 0, i2 = 0;

    #pragma unroll 4
    for (int m = 0; m < M; ++m) {
        const float sx = sp[3 * m + 0];
        const float sy = sp[3 * m + 1];
        const float sz = sp[3 * m + 2];
        const float dx = __fsub_rn(x, sx);
        const float dy = __fsub_rn(y, sy);
        const float dz = __fsub_rn(z, sz);
        const float d  = __fadd_rn(__fadd_rn(__fmul_rn(dx, dx), __fmul_rn(dy, dy)),
                                   __fmul_rn(dz, dz));
        // Strict < insertion: equal values keep the earlier (lower) index,
        // matching jax.lax.top_k tie-breaking.
        const bool lt0 = d < d0, lt1 = d < d1, lt2 = d < d2;
        d2 = lt1 ? d1 : (lt2 ? d : d2);
        i2 = lt1 ? i1 : (lt2 ? m : i2);
        d1 = lt0 ? d0 : (lt1 ? d : d1);
        i1 = lt0 ? i0 : (lt1 ? m : i1);
        d0 = lt0 ? d  : d0;
        i0 = lt0 ? m  : i0;
    }

    // IDW weights (P=2): w = 1/(max(d,1e-10)^2 + 1e-10), normalized.
    const float m0 = fmaxf(d0, 1e-10f);
    const float m1 = fmaxf(d1, 1e-10f);
    const float m2 = fmaxf(d2, 1e-10f);
    float w0 = 1.0f / (m0 * m0 + 1e-10f);
    float w1 = 1.0f / (m1 * m1 + 1e-10f);
    float w2 = 1.0f / (m2 * m2 + 1e-10f);
    const float scale = valid ? (1.0f / (w0 + w1 + w2)) : 0.0f;
    w0 *= scale; w1 *= scale; w2 *= scale;

    __shared__ float s_w[256][3];
    __shared__ int   s_i[256][4];   // i0, i1, i2, valid
    s_w[tid][0] = w0; s_w[tid][1] = w1; s_w[tid][2] = w2;
    s_i[tid][0] = i0;
    s_i[tid][1] = i1;
    s_i[tid][2] = i2;
    s_i[tid][3] = valid;
    __syncthreads();

    // ---- Phase 2: gather + weighted sum, thread = channel ----
    const float* Fb = feats + (size_t)b * (M * C);
    const int c = tid;                                   // C == blockDim.x
    float* op = out + (((size_t)b * N + nbase) * C) + c; // coalesced stores

    for (int p = 0; p < 256; ++p) {
        float r = 0.0f;
        if (s_i[p][3]) {            // block-uniform branch: skip masked rows
            const int j0 = s_i[p][0], j1 = s_i[p][1], j2 = s_i[p][2];
            r =      s_w[p][0] * Fb[j0 * C + c];
            r = fmaf(s_w[p][1],  Fb[j1 * C + c], r);
            r = fmaf(s_w[p][2],  Fb[j2 * C + c], r);
        }
        op[(size_t)p * C] = r;
    }
}

extern "C" void kernel_launch(void* const* d_in, const int* in_sizes, int n_in,
                              void* d_out, int out_size, void* d_ws, size_t ws_size,
                              hipStream_t stream) {
    const float* xyz   = (const float*)d_in[0];
    const float* sxyz  = (const float*)d_in[1];
    const float* feats = (const float*)d_in[2];
    const int*   masks = (const int*)d_in[3];
    float*       out   = (float*)d_out;

    dim3 grid(B * N / 256);   // 512 blocks
    dim3 block(256);
    hipLaunchKernelGGL(upsample_idw_kernel, grid, block, 0, stream,
                       xyz, sxyz, feats, masks, out);
}

// Round 3
// 100.202 us; speedup vs baseline: 1.8161x; 1.8161x over previous
//
#include <hip/hip_runtime.h>

// Problem constants (from reference setup_inputs).
constexpr int B = 8;
constexpr int N = 16384;
constexpr int M = 1024;
constexpr int C = 256;
constexpr int PTS = 64;   // points per block
constexpr int QW  = 4;    // candidate quarters (= waves per block), M/QW = 256 each

// Block = 256 threads = 4 waves.
// Phase 1: wave w computes, for each of the block's 64 points (one per lane),
//          a top-3 over candidate quarter [w*256, (w+1)*256). Candidate reads
//          are wave-uniform -> scalar-load path.
// Merge:   packed (dist_bits<<32 | idx) uint64 keys, exact top_k tie-break.
// Phase 2: thread = channel, coalesced gathers + stores.
__global__ __launch_bounds__(256) void upsample_idw_kernel(
    const float* __restrict__ xyz,          // [B,N,3]
    const float* __restrict__ sxyz,         // [B,M,3]
    const float* __restrict__ feats,        // [B,M,C]
    const int*   __restrict__ masks,        // [B,N]
    float*       __restrict__ out)          // [B,N,C]
{
    const int tid = threadIdx.x;
    const int w   = tid >> 6;               // wave id = candidate quarter
    const int l   = tid & 63;               // point within block
    const int blk = blockIdx.x;
    const int b     = blk >> 8;             // 16384/64 = 256 blocks per batch
    const int nbase = (blk & 255) << 6;     // first point of this block

    __shared__ unsigned long long s_key[PTS][QW][3];
    __shared__ float s_w[PTS][3];
    __shared__ int   s_j[PTS][4];           // j0, j1, j2, valid

    // ---- Phase 1: per-(point, quarter) top-3 ----
    const int n = nbase + l;
    const float* xp = xyz + ((size_t)b * N + n) * 3;
    const float x = xp[0], y = xp[1], z = xp[2];

    const float* sp = sxyz + (size_t)b * (M * 3) + (size_t)w * 256 * 3; // wave-uniform

    // Distance must BIT-MATCH the reference: (dx*dx + dy*dy) + dz*dz, no fma.
    float d0 = __builtin_inff(), d1 = __builtin_inff(), d2 = __builtin_inff();
    int   i0 = 0, i1 = 0, i2 = 0;

    #pragma unroll 4
    for (int m = 0; m < 256; ++m) {
        const float sx = sp[3 * m + 0];
        const float sy = sp[3 * m + 1];
        const float sz = sp[3 * m + 2];
        const float dx = __fsub_rn(x, sx);
        const float dy = __fsub_rn(y, sy);
        const float dz = __fsub_rn(z, sz);
        const float d  = __fadd_rn(__fadd_rn(__fmul_rn(dx, dx), __fmul_rn(dy, dy)),
                                   __fmul_rn(dz, dz));
        // Strict < keeps earlier (lower) index on ties.
        const bool lt0 = d < d0, lt1 = d < d1, lt2 = d < d2;
        d2 = lt1 ? d1 : (lt2 ? d : d2);
        i2 = lt1 ? i1 : (lt2 ? m : i2);
        d1 = lt0 ? d0 : (lt1 ? d : d1);
        i1 = lt0 ? i0 : (lt1 ? m : i1);
        d0 = lt0 ? d  : d0;
        i0 = lt0 ? m  : i0;
    }

    // Pack (dist_bits, global_idx) into uint64: monotone for d >= 0,
    // lexicographic tie-break = lowest index, matching jax.lax.top_k.
    const unsigned base = (unsigned)(w * 256);
    s_key[l][w][0] = ((unsigned long long)__float_as_uint(d0) << 32) | (base + (unsigned)i0);
    s_key[l][w][1] = ((unsigned long long)__float_as_uint(d1) << 32) | (base + (unsigned)i1);
    s_key[l][w][2] = ((unsigned long long)__float_as_uint(d2) << 32) | (base + (unsigned)i2);
    __syncthreads();

    // ---- Merge: 12 candidates -> top-3 (one thread per point) ----
    if (tid < PTS) {
        unsigned long long k0 = ~0ULL, k1 = ~0ULL, k2 = ~0ULL;
        #pragma unroll
        for (int q = 0; q < QW; ++q) {
            #pragma unroll
            for (int s = 0; s < 3; ++s) {
                const unsigned long long k = s_key[tid][q][s];
                const bool lt0 = k < k0, lt1 = k < k1, lt2 = k < k2;
                k2 = lt1 ? k1 : (lt2 ? k : k2);
                k1 = lt0 ? k0 : (lt1 ? k : k1);
                k0 = lt0 ? k  : k0;
            }
        }
        const float e0 = __uint_as_float((unsigned)(k0 >> 32));
        const float e1 = __uint_as_float((unsigned)(k1 >> 32));
        const float e2 = __uint_as_float((unsigned)(k2 >> 32));
        const float m0 = fmaxf(e0, 1e-10f);
        const float m1 = fmaxf(e1, 1e-10f);
        const float m2 = fmaxf(e2, 1e-10f);
        float w0 = 1.0f / (m0 * m0 + 1e-10f);
        float w1 = 1.0f / (m1 * m1 + 1e-10f);
        float w2 = 1.0f / (m2 * m2 + 1e-10f);
        const int valid = masks[(size_t)b * N + nbase + tid];
        const float scale = valid ? (1.0f / (w0 + w1 + w2)) : 0.0f;
        s_w[tid][0] = w0 * scale;
        s_w[tid][1] = w1 * scale;
        s_w[tid][2] = w2 * scale;
        s_j[tid][0] = (int)(unsigned)k0;
        s_j[tid][1] = (int)(unsigned)k1;
        s_j[tid][2] = (int)(unsigned)k2;
        s_j[tid][3] = valid;
    }
    __syncthreads();

    // ---- Phase 2: gather + weighted sum, thread = channel ----
    const float* Fb = feats + (size_t)b * (M * C) + tid;       // c = tid
    float* op = out + (((size_t)b * N + nbase) * C) + tid;     // coalesced

    for (int p = 0; p < PTS; ++p) {
        float r = 0.0f;
        if (s_j[p][3]) {            // block-uniform branch
            r =      s_w[p][0] * Fb[s_j[p][0] * C];
            r = fmaf(s_w[p][1],  Fb[s_j[p][1] * C], r);
            r = fmaf(s_w[p][2],  Fb[s_j[p][2] * C], r);
        }
        op[(size_t)p * C] = r;
    }
}

extern "C" void kernel_launch(void* const* d_in, const int* in_sizes, int n_in,
                              void* d_out, int out_size, void* d_ws, size_t ws_size,
                              hipStream_t stream) {
    const float* xyz   = (const float*)d_in[0];
    const float* sxyz  = (const float*)d_in[1];
    const float* feats = (const float*)d_in[2];
    const int*   masks = (const int*)d_in[3];
    float*       out   = (float*)d_out;

    dim3 grid(B * N / PTS);   // 2048 blocks
    dim3 block(256);
    hipLaunchKernelGGL(upsample_idw_kernel, grid, block, 0, stream,
                       xyz, sxyz, feats, masks, out);
}

// Round 4
// 85.140 us; speedup vs baseline: 2.1373x; 1.1769x over previous
//
#include <hip/hip_runtime.h>

// Problem constants (from reference setup_inputs).
constexpr int B = 8;
constexpr int N = 16384;
constexpr int M = 1024;
constexpr int C = 256;
constexpr int PTS = 64;   // points per block
constexpr int QW  = 4;    // candidate quarters (= waves per block), M/QW = 256 each

// Block = 256 threads = 4 waves.
// Phase 1: wave w computes, for each of the block's 64 points (one per lane),
//          a top-3 over candidate quarter [w*256, (w+1)*256). Candidate
//          addresses are made PROVABLY wave-uniform via readfirstlane so the
//          compiler emits scalar (s_load) candidate reads -> no VALU/VMEM cost.
// Merge:   packed (dist_bits<<32 | idx) uint64 keys, exact top_k tie-break.
// Phase 2: thread = channel, scalar indices/weights via readfirstlane,
//          coalesced gathers + stores.
__global__ __launch_bounds__(256) void upsample_idw_kernel(
    const float* __restrict__ xyz,          // [B,N,3]
    const float* __restrict__ sxyz,         // [B,M,3]
    const float* __restrict__ feats,        // [B,M,C]
    const int*   __restrict__ masks,        // [B,N]
    float*       __restrict__ out)          // [B,N,C]
{
    const int tid = threadIdx.x;
    const int w   = __builtin_amdgcn_readfirstlane(tid >> 6); // SGPR wave id
    const int l   = tid & 63;               // point within block
    const int blk = blockIdx.x;
    const int b     = blk >> 8;             // 16384/64 = 256 blocks per batch
    const int nbase = (blk & 255) << 6;     // first point of this block

    __shared__ unsigned long long s_key[PTS][QW][3];
    __shared__ float s_w[PTS][3];
    __shared__ int   s_j[PTS][4];           // j0, j1, j2, valid

    // ---- Phase 1: per-(point, quarter) top-3 ----
    const int n = nbase + l;
    const float* xp = xyz + ((size_t)b * N + n) * 3;
    const float x = xp[0], y = xp[1], z = xp[2];

    // Wave-uniform candidate pointer (b, w both SGPR) -> scalar loads.
    const float* sp = sxyz + (size_t)b * (M * 3) + (size_t)w * (256 * 3);

    // Distance must BIT-MATCH the reference: (dx*dx + dy*dy) + dz*dz, no fma.
    float d0 = __builtin_inff(), d1 = __builtin_inff(), d2 = __builtin_inff();
    int   i0 = 0, i1 = 0, i2 = 0;

    #pragma unroll 8
    for (int m = 0; m < 256; ++m) {
        const float sx = sp[3 * m + 0];
        const float sy = sp[3 * m + 1];
        const float sz = sp[3 * m + 2];
        const float dx = __fsub_rn(x, sx);
        const float dy = __fsub_rn(y, sy);
        const float dz = __fsub_rn(z, sz);
        const float d  = __fadd_rn(__fadd_rn(__fmul_rn(dx, dx), __fmul_rn(dy, dy)),
                                   __fmul_rn(dz, dz));
        // Strict < keeps earlier (lower) index on ties (matches top_k).
        const bool lt0 = d < d0, lt1 = d < d1, lt2 = d < d2;
        // Index ladder (uses OLD i's).
        i2 = lt1 ? i1 : (lt2 ? m : i2);
        i1 = lt0 ? i0 : (lt1 ? m : i1);
        i0 = lt0 ? m  : i0;
        // Value ladder via exact min/med3 selection (no rounding involved):
        //   d2' = med3(d1, d2, d); d1' = med3(d0, d1, d); d0' = min(d0, d).
        const float nd2 = __builtin_amdgcn_fmed3f(d1, d2, d);
        const float nd1 = __builtin_amdgcn_fmed3f(d0, d1, d);
        d2 = nd2;
        d1 = nd1;
        d0 = fminf(d0, d);
    }

    // Pack (dist_bits, global_idx) into uint64: monotone for d >= 0,
    // lexicographic tie-break = lowest index, matching jax.lax.top_k.
    const unsigned base = (unsigned)(w * 256);
    s_key[l][w][0] = ((unsigned long long)__float_as_uint(d0) << 32) | (base + (unsigned)i0);
    s_key[l][w][1] = ((unsigned long long)__float_as_uint(d1) << 32) | (base + (unsigned)i1);
    s_key[l][w][2] = ((unsigned long long)__float_as_uint(d2) << 32) | (base + (unsigned)i2);
    __syncthreads();

    // ---- Merge: 12 candidates -> top-3 (one thread per point) ----
    if (tid < PTS) {
        unsigned long long k0 = ~0ULL, k1 = ~0ULL, k2 = ~0ULL;
        #pragma unroll
        for (int q = 0; q < QW; ++q) {
            #pragma unroll
            for (int s = 0; s < 3; ++s) {
                const unsigned long long k = s_key[tid][q][s];
                const bool lt0 = k < k0, lt1 = k < k1, lt2 = k < k2;
                k2 = lt1 ? k1 : (lt2 ? k : k2);
                k1 = lt0 ? k0 : (lt1 ? k : k1);
                k0 = lt0 ? k  : k0;
            }
        }
        const float e0 = __uint_as_float((unsigned)(k0 >> 32));
        const float e1 = __uint_as_float((unsigned)(k1 >> 32));
        const float e2 = __uint_as_float((unsigned)(k2 >> 32));
        const float m0 = fmaxf(e0, 1e-10f);
        const float m1 = fmaxf(e1, 1e-10f);
        const float m2 = fmaxf(e2, 1e-10f);
        float w0 = 1.0f / (m0 * m0 + 1e-10f);
        float w1 = 1.0f / (m1 * m1 + 1e-10f);
        float w2 = 1.0f / (m2 * m2 + 1e-10f);
        const int valid = masks[(size_t)b * N + nbase + tid];
        const float scale = valid ? (1.0f / (w0 + w1 + w2)) : 0.0f;
        s_w[tid][0] = w0 * scale;
        s_w[tid][1] = w1 * scale;
        s_w[tid][2] = w2 * scale;
        s_j[tid][0] = (int)(unsigned)k0;
        s_j[tid][1] = (int)(unsigned)k1;
        s_j[tid][2] = (int)(unsigned)k2;
        s_j[tid][3] = valid;
    }
    __syncthreads();

    // ---- Phase 2: gather + weighted sum, thread = channel ----
    const float* Fb = feats + (size_t)b * (M * C) + tid;       // c = tid
    float* op = out + (((size_t)b * N + nbase) * C) + tid;     // coalesced

    for (int p = 0; p < PTS; ++p) {
        // All lanes read the same LDS slots -> lift to SGPRs explicitly.
        const int vld = __builtin_amdgcn_readfirstlane(s_j[p][3]);
        float r = 0.0f;
        if (vld) {   // scalar branch
            const int j0 = __builtin_amdgcn_readfirstlane(s_j[p][0]);
            const int j1 = __builtin_amdgcn_readfirstlane(s_j[p][1]);
            const int j2 = __builtin_amdgcn_readfirstlane(s_j[p][2]);
            const float w0 = __uint_as_float(
                __builtin_amdgcn_readfirstlane((int)__float_as_uint(s_w[p][0])));
            const float w1 = __uint_as_float(
                __builtin_amdgcn_readfirstlane((int)__float_as_uint(s_w[p][1])));
            const float w2 = __uint_as_float(
                __builtin_amdgcn_readfirstlane((int)__float_as_uint(s_w[p][2])));
            r =      w0 * Fb[j0 * C];
            r = fmaf(w1,  Fb[j1 * C], r);
            r = fmaf(w2,  Fb[j2 * C], r);
        }
        op[(size_t)p * C] = r;
    }
}

extern "C" void kernel_launch(void* const* d_in, const int* in_sizes, int n_in,
                              void* d_out, int out_size, void* d_ws, size_t ws_size,
                              hipStream_t stream) {
    const float* xyz   = (const float*)d_in[0];
    const float* sxyz  = (const float*)d_in[1];
    const float* feats = (const float*)d_in[2];
    const int*   masks = (const int*)d_in[3];
    float*       out   = (float*)d_out;

    dim3 grid(B * N / PTS);   // 2048 blocks
    dim3 block(256);
    hipLaunchKernelGGL(upsample_idw_kernel, grid, block, 0, stream,
                       xyz, sxyz, feats, masks, out);
}

// Round 5
// 72.966 us; speedup vs baseline: 2.4940x; 1.1669x over previous
//
#include <hip/hip_runtime.h>

// Problem constants (from reference setup_inputs).
constexpr int B = 8;
constexpr int N = 16384;
constexpr int M = 1024;
constexpr int C = 256;
constexpr int PTS = 64;   // points per block
constexpr int QW  = 4;    // candidate quarters (= waves per block), M/QW = 256 each

// Block = 256 threads = 4 waves, 8 blocks/CU (LDS 14KB, VGPR <= 64).
// Stage:   batch's 1024 candidate coords (12KB) -> LDS, coalesced float4.
// Phase 1: wave w scans quarter [w*256,(w+1)*256) from LDS at wave-uniform
//          addresses (HW broadcast, LGKM pipe, zero VALU/VMEM cost).
//          Distance arithmetic bit-matches the reference (no fma).
// Merge:   packed (dist_bits<<32 | idx) u64 keys, exact top_k tie-break.
// Phase 2: 4 points x 64 channel-quads per iter, float4 gathers + stores.
__global__ __launch_bounds__(256, 8) void upsample_idw_kernel(
    const float* __restrict__ xyz,          // [B,N,3]
    const float* __restrict__ sxyz,         // [B,M,3]
    const float* __restrict__ feats,        // [B,M,C]
    const int*   __restrict__ masks,        // [B,N]
    float*       __restrict__ out)          // [B,N,C]
{
    const int tid = threadIdx.x;
    const int w   = tid >> 6;               // wave id = candidate quarter
    const int l   = tid & 63;               // point within block
    const int blk = blockIdx.x;
    const int b     = blk >> 8;             // 16384/64 = 256 blocks per batch
    const int nbase = (blk & 255) << 6;     // first point of this block

    // 12KB shared buffer: phase 1 = candidate coords [M][3] f32;
    // merge phase = u64 keys [PTS][QW][3] (6KB) after a barrier.
    __shared__ char s_mem[M * 3 * 4];
    float* s_cand = (float*)s_mem;
    unsigned long long (*s_key)[QW][3] = (unsigned long long (*)[QW][3])s_mem;
    __shared__ float s_w[PTS][3];
    __shared__ int   s_j[PTS][4];           // j0, j1, j2, valid

    // ---- Stage candidates: 768 float4 across 256 threads ----
    {
        const float4* src = (const float4*)(sxyz + (size_t)b * (M * 3));
        float4* dst = (float4*)s_mem;
        #pragma unroll
        for (int i = 0; i < 3; ++i)
            dst[tid + 256 * i] = src[tid + 256 * i];
    }

    // Point coords + mask (independent of LDS; issue before the barrier).
    const int n = nbase + l;
    const float* xp = xyz + ((size_t)b * N + n) * 3;
    const float x = xp[0], y = xp[1], z = xp[2];
    __syncthreads();

    // ---- Phase 1: per-(point, quarter) top-3 from LDS ----
    const float* cp = s_cand + w * (256 * 3);   // wave-uniform base

    float d0 = __builtin_inff(), d1 = __builtin_inff(), d2 = __builtin_inff();
    int   i0 = 0, i1 = 0, i2 = 0;

    #pragma unroll 4
    for (int m = 0; m < 256; ++m) {
        const float sx = cp[3 * m + 0];     // ds_read_b32, imm offset, broadcast
        const float sy = cp[3 * m + 1];
        const float sz = cp[3 * m + 2];
        const float dx = __fsub_rn(x, sx);
        const float dy = __fsub_rn(y, sy);
        const float dz = __fsub_rn(z, sz);
        const float d  = __fadd_rn(__fadd_rn(__fmul_rn(dx, dx), __fmul_rn(dy, dy)),
                                   __fmul_rn(dz, dz));
        // Strict < keeps earlier (lower) index on ties (matches top_k).
        const bool lt0 = d < d0, lt1 = d < d1, lt2 = d < d2;
        i2 = lt1 ? i1 : (lt2 ? m : i2);
        i1 = lt0 ? i0 : (lt1 ? m : i1);
        i0 = lt0 ? m  : i0;
        // Exact value ladder: min + 2x med3 (selection only, no rounding).
        const float nd2 = __builtin_amdgcn_fmed3f(d1, d2, d);
        const float nd1 = __builtin_amdgcn_fmed3f(d0, d1, d);
        d2 = nd2;
        d1 = nd1;
        d0 = fminf(d0, d);
    }
    __syncthreads();    // everyone done READING s_cand before keys overwrite it

    // Pack (dist_bits, global_idx): monotone u64, lowest-index tie-break.
    const unsigned base = (unsigned)(w * 256);
    s_key[l][w][0] = ((unsigned long long)__float_as_uint(d0) << 32) | (base + (unsigned)i0);
    s_key[l][w][1] = ((unsigned long long)__float_as_uint(d1) << 32) | (base + (unsigned)i1);
    s_key[l][w][2] = ((unsigned long long)__float_as_uint(d2) << 32) | (base + (unsigned)i2);
    __syncthreads();

    // ---- Merge: 12 candidates -> top-3 (one thread per point) ----
    if (tid < PTS) {
        unsigned long long k0 = ~0ULL, k1 = ~0ULL, k2 = ~0ULL;
        #pragma unroll
        for (int q = 0; q < QW; ++q) {
            #pragma unroll
            for (int s = 0; s < 3; ++s) {
                const unsigned long long k = s_key[tid][q][s];
                const bool lt0 = k < k0, lt1 = k < k1, lt2 = k < k2;
                k2 = lt1 ? k1 : (lt2 ? k : k2);
                k1 = lt0 ? k0 : (lt1 ? k : k1);
                k0 = lt0 ? k  : k0;
            }
        }
        const float e0 = __uint_as_float((unsigned)(k0 >> 32));
        const float e1 = __uint_as_float((unsigned)(k1 >> 32));
        const float e2 = __uint_as_float((unsigned)(k2 >> 32));
        const float m0 = fmaxf(e0, 1e-10f);
        const float m1 = fmaxf(e1, 1e-10f);
        const float m2 = fmaxf(e2, 1e-10f);
        float w0 = 1.0f / (m0 * m0 + 1e-10f);
        float w1 = 1.0f / (m1 * m1 + 1e-10f);
        float w2 = 1.0f / (m2 * m2 + 1e-10f);
        const int valid = masks[(size_t)b * N + nbase + tid];
        const float scale = valid ? (1.0f / (w0 + w1 + w2)) : 0.0f;
        s_w[tid][0] = w0 * scale;
        s_w[tid][1] = w1 * scale;
        s_w[tid][2] = w2 * scale;
        s_j[tid][0] = (int)(unsigned)k0;
        s_j[tid][1] = (int)(unsigned)k1;
        s_j[tid][2] = (int)(unsigned)k2;
        s_j[tid][3] = valid;
    }
    __syncthreads();

    // ---- Phase 2: 4 points x 64 channel-quads per iteration ----
    const int pq = tid >> 6;                 // sub-point (= wave id)
    const int cq = tid & 63;                 // channel quad
    const float4* Fb4 = (const float4*)(feats + (size_t)b * (M * C));
    float4* op4 = (float4*)(out + (((size_t)b * N + nbase) * C));

    for (int p0 = 0; p0 < PTS; p0 += 4) {
        const int p = p0 + pq;               // wave-uniform
        const int vld = __builtin_amdgcn_readfirstlane(s_j[p][3]);
        float4 acc = make_float4(0.f, 0.f, 0.f, 0.f);
        if (vld) {                           // scalar branch
            const int j0 = __builtin_amdgcn_readfirstlane(s_j[p][0]);
            const int j1 = __builtin_amdgcn_readfirstlane(s_j[p][1]);
            const int j2 = __builtin_amdgcn_readfirstlane(s_j[p][2]);
            const float w0 = __uint_as_float(
                __builtin_amdgcn_readfirstlane((int)__float_as_uint(s_w[p][0])));
            const float w1 = __uint_as_float(
                __builtin_amdgcn_readfirstlane((int)__float_as_uint(s_w[p][1])));
            const float w2 = __uint_as_float(
                __builtin_amdgcn_readfirstlane((int)__float_as_uint(s_w[p][2])));
            const float4 f0 = Fb4[j0 * 64 + cq];
            const float4 f1 = Fb4[j1 * 64 + cq];
            const float4 f2 = Fb4[j2 * 64 + cq];
            acc.x = fmaf(w2, f2.x, fmaf(w1, f1.x, w0 * f0.x));
            acc.y = fmaf(w2, f2.y, fmaf(w1, f1.y, w0 * f0.y));
            acc.z = fmaf(w2, f2.z, fmaf(w1, f1.z, w0 * f0.z));
            acc.w = fmaf(w2, f2.w, fmaf(w1, f1.w, w0 * f0.w));
        }
        op4[p * 64 + cq] = acc;
    }
}

extern "C" void kernel_launch(void* const* d_in, const int* in_sizes, int n_in,
                              void* d_out, int out_size, void* d_ws, size_t ws_size,
                              hipStream_t stream) {
    const float* xyz   = (const float*)d_in[0];
    const float* sxyz  = (const float*)d_in[1];
    const float* feats = (const float*)d_in[2];
    const int*   masks = (const int*)d_in[3];
    float*       out   = (float*)d_out;

    dim3 grid(B * N / PTS);   // 2048 blocks
    dim3 block(256);
    hipLaunchKernelGGL(upsample_idw_kernel, grid, block, 0, stream,
                       xyz, sxyz, feats, masks, out);
}